// Round 5
// baseline (28.009 us; speedup 1.0000x reference)
//
#include <hip/hip_runtime.h>
#include <hip/hip_fp16.h>

#define HOURS 24
#define RPB 256          // rows per block tile
#define PSTR 25          // dwords per row in LDS: 24 half2 + 1 pad (gcd(25,32)=1 -> conflict-free reads)

// Workspace layout: float partials[6][num_blocks]
// 0: sum (yp-yt)^2 all | 1: sum (yp-yt)^2 daytime | 2: sum (p_pv-t_pv)^2
// 3: sum (p_pt-t_pt)^2 | 4: sum mse_win (valid)   | 5: count valid

__global__ __launch_bounds__(256, 6) void peakloss_main(
    const float* __restrict__ ypred, const float* __restrict__ ytrue,
    float* __restrict__ partials, int nrows, int nblocks) {
  __shared__ __half2 ltp[RPB * PSTR];   // 25.6 KB -> 6 blocks/CU

  const int tid = threadIdx.x;
  const int tile0 = blockIdx.x * RPB;
  const int rows = min(RPB, nrows - tile0);

  // ---- stage: coalesced float4 global loads -> packed half2(t,p) in padded LDS ----
  if (rows == RPB) {
    const float4* t4 = (const float4*)(ytrue + (size_t)tile0 * HOURS);
    const float4* p4 = (const float4*)(ypred + (size_t)tile0 * HOURS);
#pragma unroll
    for (int j = 0; j < 6; ++j) {
      int f4 = tid + j * 256;            // lane-contiguous float4 index
      float4 a = t4[f4];
      float4 b = p4[f4];
      // dword group [4*f4, 4*f4+3] never crosses a row boundary (24 % 4 == 0);
      // padded addr = d + d/24, and (4*f4)/24 == f4/6.
      int pa0 = f4 * 4 + f4 / 6;
      ltp[pa0 + 0] = __floats2half2_rn(a.x, b.x);
      ltp[pa0 + 1] = __floats2half2_rn(a.y, b.y);
      ltp[pa0 + 2] = __floats2half2_rn(a.z, b.z);
      ltp[pa0 + 3] = __floats2half2_rn(a.w, b.w);
    }
  } else {
    for (int d = tid; d < rows * HOURS; d += 256) {
      int pa = d + d / HOURS;
      ltp[pa] = __floats2half2_rn(ytrue[(size_t)tile0 * HOURS + d],
                                  ypred[(size_t)tile0 * HOURS + d]);
    }
  }
  __syncthreads();

  float s_sq = 0.f, s_day = 0.f, s_pv = 0.f, s_pt = 0.f, s_shape = 0.f, s_valid = 0.f;

  if (tid < rows) {
    const __half2* row = ltp + tid * PSTR;

    // ---- pass 1: mse sums + daytime max/argmax (first-max semantics) ----
    float mt = -1e30f, mp = -1e30f;
    int idx = 6;
#pragma unroll
    for (int h = 0; h < HOURS; ++h) {
      __half2 v = row[h];
      float th = __low2float(v), ph = __high2float(v);
      float d = ph - th;
      float dd = d * d;
      s_sq += dd;
      if (h >= 6 && h <= 20) {
        s_day += dd;
        if (th > mt) { mt = th; idx = h; }
        mp = fmaxf(mp, ph);
      }
    }

    // ---- pass 2: softmax sums (T=0.1) + window maxima ----
    int ws = idx - 2;                    // in [4,18]; window [ws, ws+5) in [4,23)
    float den_t = 0.f, nv_t = 0.f, nt_t = 0.f;
    float den_p = 0.f, nv_p = 0.f, nt_p = 0.f;
    float tmax = -1e30f, pmax = -1e30f;
#pragma unroll
    for (int h = 4; h <= 22; ++h) {
      __half2 v = row[h];
      float th = __low2float(v), ph = __high2float(v);
      if (h >= 6 && h <= 20) {
        float et = __expf((th - mt) * 10.f);
        den_t += et; nv_t += et * th; nt_t += et * (float)h;
        float ep = __expf((ph - mp) * 10.f);
        den_p += ep; nv_p += ep * ph; nt_p += ep * (float)h;
      }
      bool in = (h >= ws) & (h < ws + 5);
      if (in) { tmax = fmaxf(tmax, th); pmax = fmaxf(pmax, ph); }
    }
    float r_t = __builtin_amdgcn_rcpf(den_t);
    float r_p = __builtin_amdgcn_rcpf(den_p);
    float dv  = nv_p * r_p - nv_t * r_t;
    float dtm = nt_p * r_p - nt_t * r_t;
    s_pv += dv * dv;
    s_pt += dtm * dtm;

    // ---- pass 3: windowed normalized shape mse ----
    bool valid = tmax > 1e-6f;
    float tms = valid ? tmax : 1.0f;
    float r_tms  = __builtin_amdgcn_rcpf(tms);
    float r_pden = __builtin_amdgcn_rcpf(pmax + 1e-6f);
    float a = 0.f;
#pragma unroll
    for (int h = 4; h <= 22; ++h) {
      __half2 v = row[h];
      float th = __low2float(v), ph = __high2float(v);
      bool in = (h >= ws) & (h < ws + 5);
      float d = ph * r_pden - th * r_tms;
      a += in ? d * d : 0.f;
    }
    if (valid) { s_shape += a * 0.2f; s_valid += 1.0f; }
  }

  // ---- block reduction: wave shuffle -> LDS across 4 waves -> per-block write ----
  float v[6] = {s_sq, s_day, s_pv, s_pt, s_shape, s_valid};
#pragma unroll
  for (int j = 0; j < 6; ++j) {
#pragma unroll
    for (int off = 32; off >= 1; off >>= 1) v[j] += __shfl_down(v[j], off, 64);
  }
  __shared__ float red[6][4];
  int lane = threadIdx.x & 63, wave = threadIdx.x >> 6;
  __syncthreads();
  if (lane == 0) {
#pragma unroll
    for (int j = 0; j < 6; ++j) red[j][wave] = v[j];
  }
  __syncthreads();
  if (threadIdx.x < 6) {
    int j = threadIdx.x;
    partials[(size_t)j * nblocks + blockIdx.x] =
        red[j][0] + red[j][1] + red[j][2] + red[j][3];
  }
}

// Single-block final reduction in fp64; writes the scalar loss.
__global__ __launch_bounds__(256) void peakloss_reduce(
    const float* __restrict__ partials, float* __restrict__ out,
    int nblocks, double inv_BS, double inv_BD) {
  double s[6] = {0, 0, 0, 0, 0, 0};
  for (int i = threadIdx.x; i < nblocks; i += 256) {
#pragma unroll
    for (int j = 0; j < 6; ++j) s[j] += (double)partials[(size_t)j * nblocks + i];
  }
#pragma unroll
  for (int j = 0; j < 6; ++j) {
#pragma unroll
    for (int off = 32; off >= 1; off >>= 1) s[j] += __shfl_down(s[j], off, 64);
  }
  __shared__ double red[6][4];
  int lane = threadIdx.x & 63, wave = threadIdx.x >> 6;
  if (lane == 0) {
#pragma unroll
    for (int j = 0; j < 6; ++j) red[j][wave] = s[j];
  }
  __syncthreads();
  if (threadIdx.x == 0) {
    double a[6];
#pragma unroll
    for (int j = 0; j < 6; ++j)
      a[j] = red[j][0] + red[j][1] + red[j][2] + red[j][3];
    double L_overall = a[0] * inv_BS;
    double L_day     = a[1] * inv_BS;          // weighted_mse - L_overall
    double L_pv      = a[2] * inv_BD;
    double L_pt      = a[3] * inv_BD;
    double L_shape   = a[4] / (a[5] + 1e-6);
    out[0] = (float)(L_overall + 2.0 * L_pv + L_pt + 0.5 * L_shape + 0.5 * L_day);
  }
}

extern "C" void kernel_launch(void* const* d_in, const int* in_sizes, int n_in,
                              void* d_out, int out_size, void* d_ws, size_t ws_size,
                              hipStream_t stream) {
  const float* ypred = (const float*)d_in[0];
  const float* ytrue = (const float*)d_in[1];
  float* out = (float*)d_out;
  float* partials = (float*)d_ws;

  long long N = in_sizes[0];          // B * S
  int nrows = (int)(N / HOURS);       // B * D
  int grid = (nrows + RPB - 1) / RPB; // 1920 for the bench shape

  peakloss_main<<<grid, 256, 0, stream>>>(ypred, ytrue, partials, nrows, grid);

  double inv_BS = 1.0 / (double)N;
  double inv_BD = 1.0 / (double)nrows;
  peakloss_reduce<<<1, 256, 0, stream>>>(partials, out, grid, inv_BS, inv_BD);
}